// Round 7
// baseline (648.490 us; speedup 1.0000x reference)
//
#include <hip/hip_runtime.h>
#include <math.h>

#define S_LEN 2048
#define ENC2  1024
#define DEC_H 1024
#define ATT   1024
#define BATCH 32

typedef __attribute__((ext_vector_type(8)))  short short8;
typedef __attribute__((ext_vector_type(4)))  short s4;
typedef __attribute__((ext_vector_type(16))) float f32x16;

// ws layout: BP 2MB @0 | dp 128KB @2MB | ctx partials 4MB @4MB | Apack 128MB @8MB
#define DP_OFF  (2u << 20)
#define CTX_OFF (4u << 20)
#define AP_OFF  (8u << 20)
#define NEED_CTX  ((size_t)(8u << 20))
#define NEED_FULL ((size_t)(8u << 20) + 134217728ull)

__device__ __forceinline__ unsigned short f2bf(float f) {
    unsigned int u = __float_as_uint(f);
    return (unsigned short)((u + 0x7FFFu + ((u >> 16) & 1u)) >> 16);  // RNE
}

__device__ __forceinline__ float tanh_fast(float x) {
    float ax = fabsf(x);
    float e = __expf(-2.0f * ax);
    float t = (1.0f - e) / (1.0f + e);
    return copysignf(t, x);
}

__device__ __forceinline__ void gload16(const void* g, void* l) {
    __builtin_amdgcn_global_load_lds(
        (const __attribute__((address_space(1))) void*)g,
        (__attribute__((address_space(3))) void*)l, 16, 0, 0);
}

// ---- fragment-pack W_enc -> P[kb][nb][lane][j] ----
__global__ void k_pack(const float* __restrict__ W, unsigned short* __restrict__ P) {
    int t  = threadIdx.x;                 // 256
    int kb = blockIdx.x;                  // 64
    int nb = blockIdx.y * 4 + (t >> 6);   // 32
    int l  = t & 63;
    int n  = nb * 32 + (l & 31);
    int k0 = kb * 16 + ((l >> 5) * 8);
    short8 v;
#pragma unroll
    for (int j = 0; j < 8; ++j)
        v[j] = (short)f2bf(W[(size_t)(k0 + j) * ATT + n]);
    *(short8*)(P + (((size_t)kb * 32 + nb) * 64 + l) * 8) = v;
}

// ---- enc f32 -> pre-swizzled bf16 stripe images: Apack[stripe][ph][64r][256B] ----
__global__ void k_cvtA(const float* __restrict__ enc, char* __restrict__ AP) {
    const int tid = threadIdx.x;
#pragma unroll 1
    for (int it = 0; it < 16; ++it) {
        int g = blockIdx.x * 4096 + it * 256 + tid;   // 16B unit index, 8.39M total
        int stripe = g >> 13;
        int rem    = g & 8191;
        int ph     = rem >> 10;
        int u      = rem & 1023;
        int row    = u >> 4;
        int slot   = u & 15;
        const float* src = enc + (((size_t)stripe * 64 + row) << 10) + (ph << 7) + (slot << 3);
        float4 f0 = *(const float4*)src;
        float4 f1 = *(const float4*)(src + 4);
        short8 v;
        v[0] = (short)f2bf(f0.x); v[1] = (short)f2bf(f0.y);
        v[2] = (short)f2bf(f0.z); v[3] = (short)f2bf(f0.w);
        v[4] = (short)f2bf(f1.x); v[5] = (short)f2bf(f1.y);
        v[6] = (short)f2bf(f1.z); v[7] = (short)f2bf(f1.w);
        *(short8*)(AP + ((size_t)stripe << 17) + (ph << 14) + row * 256
                      + ((slot << 4) ^ ((row & 15) << 4))) = v;
    }
}

// ---- dproj[b][n] = dec[b]@W_dec[:,n] + b_dec[n] + b_enc[n] ----
__global__ void k_dproj(const float* __restrict__ dec, const float* __restrict__ Wd,
                        const float* __restrict__ b_dec, const float* __restrict__ b_enc,
                        float* __restrict__ dp) {
    int n = blockIdx.x * 256 + threadIdx.x;
    int b = blockIdx.y;
    const float* dh = dec + b * DEC_H;
    float a0 = 0, a1 = 0, a2 = 0, a3 = 0;
#pragma unroll 8
    for (int k = 0; k < DEC_H; k += 4) {
        a0 = fmaf(dh[k + 0], Wd[(size_t)(k + 0) * ATT + n], a0);
        a1 = fmaf(dh[k + 1], Wd[(size_t)(k + 1) * ATT + n], a1);
        a2 = fmaf(dh[k + 2], Wd[(size_t)(k + 2) * ATT + n], a2);
        a3 = fmaf(dh[k + 3], Wd[(size_t)(k + 3) * ATT + n], a3);
    }
    dp[b * ATT + n] = b_dec[n] + b_enc[n] + ((a0 + a1) + (a2 + a3));
}

// ---- FAST energy: bf16 Apack + global_load_lds staging, 8 phases K=128 ----
__launch_bounds__(256, 4)
__global__ void k_energy_f(const char* __restrict__ AP,
                           const short* __restrict__ BP,
                           const float* __restrict__ dp,
                           const float* __restrict__ w_e,
                           float* __restrict__ ew)
{
    __shared__ short As[2][64][128];   // 2 x 16 KB pre-swizzled images
    float* e_lds = (float*)As;

    const int tid    = threadIdx.x;
    const int bid    = blockIdx.x;
    const int swz    = (bid & 7) * 512 + (bid >> 3);
    const int stripe = swz >> 2;
    const int nq     = swz & 3;
    const int r0     = stripe << 6;
    const int b      = stripe >> 5;

    const int lane = tid & 63;
    const int wid  = tid >> 6;
    const int col  = lane & 31;
    const int hi   = lane >> 5;
    const int hi16 = hi << 4;
    const int xr   = (col & 15) << 4;

    float dv[2], wv[2];
#pragma unroll
    for (int nf = 0; nf < 2; ++nf) {
        int n = nq * 256 + wid * 64 + nf * 32 + col;
        dv[nf] = dp[b * ATT + n];
        wv[nf] = w_e[n];
    }

    const char* bpp    = (const char*)BP + (size_t)(nq * 8 + wid * 2) * 1024 + lane * 16;
    const char* apbase = AP + ((size_t)stripe << 17);

    f32x16 acc[2][2];
#pragma unroll
    for (int mf = 0; mf < 2; ++mf)
#pragma unroll
        for (int nf = 0; nf < 2; ++nf)
#pragma unroll
            for (int r = 0; r < 16; ++r) acc[mf][nf][r] = 0.0f;

    short8 bb0[2], bb1[2];
    bb0[0] = *(const short8*)(bpp);
    bb0[1] = *(const short8*)(bpp + 1024);
    bb1[0] = *(const short8*)(bpp + 32768);
    bb1[1] = *(const short8*)(bpp + 32768 + 1024);

    // prologue: stage phase 0 into As[0]
#pragma unroll
    for (int i = 0; i < 4; ++i)
        gload16(apbase + (wid * 4 + i) * 1024 + lane * 16,
                (short*)As + (wid * 4 + i) * 512);
    __syncthreads();

#pragma unroll 1
    for (int ph = 0; ph < 8; ++ph) {
        if (ph < 7) {
            const char* s = apbase + ((ph + 1) << 14);
            short* d = (short*)As + (((ph + 1) & 1) << 13);
#pragma unroll
            for (int i = 0; i < 4; ++i)
                gload16(s + (wid * 4 + i) * 1024 + lane * 16, d + (wid * 4 + i) * 512);
        }
        const char* ab    = (const char*)As + ((ph & 1) << 14);
        const char* arow0 = ab + col * 256;
        const char* arow1 = ab + (col + 32) * 256;
#pragma unroll
        for (int t = 0; t < 8; t += 2) {
            const int kb = (ph << 3) + t;
            {
                int off = ((t << 5) + hi16) ^ xr;
                short8 a0 = *(const short8*)(arow0 + off);
                short8 a1 = *(const short8*)(arow1 + off);
                acc[0][0] = __builtin_amdgcn_mfma_f32_32x32x16_bf16(a0, bb0[0], acc[0][0], 0, 0, 0);
                acc[0][1] = __builtin_amdgcn_mfma_f32_32x32x16_bf16(a0, bb0[1], acc[0][1], 0, 0, 0);
                acc[1][0] = __builtin_amdgcn_mfma_f32_32x32x16_bf16(a1, bb0[0], acc[1][0], 0, 0, 0);
                acc[1][1] = __builtin_amdgcn_mfma_f32_32x32x16_bf16(a1, bb0[1], acc[1][1], 0, 0, 0);
                size_t ro = (size_t)((kb + 2) & 63) << 15;
                bb0[0] = *(const short8*)(bpp + ro);
                bb0[1] = *(const short8*)(bpp + ro + 1024);
            }
            {
                int off = (((t + 1) << 5) + hi16) ^ xr;
                short8 a0 = *(const short8*)(arow0 + off);
                short8 a1 = *(const short8*)(arow1 + off);
                acc[0][0] = __builtin_amdgcn_mfma_f32_32x32x16_bf16(a0, bb1[0], acc[0][0], 0, 0, 0);
                acc[0][1] = __builtin_amdgcn_mfma_f32_32x32x16_bf16(a0, bb1[1], acc[0][1], 0, 0, 0);
                acc[1][0] = __builtin_amdgcn_mfma_f32_32x32x16_bf16(a1, bb1[0], acc[1][0], 0, 0, 0);
                acc[1][1] = __builtin_amdgcn_mfma_f32_32x32x16_bf16(a1, bb1[1], acc[1][1], 0, 0, 0);
                size_t ro = (size_t)((kb + 3) & 63) << 15;
                bb1[0] = *(const short8*)(bpp + ro);
                bb1[1] = *(const short8*)(bpp + ro + 1024);
            }
        }
        __syncthreads();
    }

    float ep[32];
#pragma unroll
    for (int mf = 0; mf < 2; ++mf)
#pragma unroll
        for (int reg = 0; reg < 16; ++reg)
            ep[mf * 16 + reg] = fmaf(wv[0], tanh_fast(acc[mf][0][reg] + dv[0]),
                                     wv[1] * tanh_fast(acc[mf][1][reg] + dv[1]));
#pragma unroll
    for (int d = 1; d < 32; d <<= 1)
#pragma unroll
        for (int j = 0; j < 32; ++j)
            ep[j] += __shfl_xor(ep[j], d, 64);

    if (tid < 64) e_lds[tid] = 0.0f;
    __syncthreads();
    if (col == 0) {
#pragma unroll
        for (int j = 0; j < 32; ++j) {
            int reg = j & 15;
            int row = (j >> 4) * 32 + (reg & 3) + 8 * (reg >> 2) + 4 * hi;
            atomicAdd(&e_lds[row], ep[j]);
        }
    }
    __syncthreads();
    if (tid < 64) atomicAdd(&ew[r0 + tid], e_lds[tid]);
}

// ---- FALLBACK energy (proven R6 path, f32 staging) ----
__launch_bounds__(256, 4)
__global__ void k_energy_v6(const float* __restrict__ enc, const short* __restrict__ BP,
                            const float* __restrict__ dp, const float* __restrict__ w_e,
                            float* __restrict__ ew)
{
    __shared__ short As[2][64][64];
    __shared__ float e_lds[64];
    const int tid = threadIdx.x;
    const int bid = blockIdx.x;
    const int swz = (bid & 7) * 512 + (bid >> 3);
    const int stripe = swz >> 2;
    const int nq = swz & 3;
    const int r0 = stripe << 6;
    const int b  = stripe >> 5;
    const int lane = tid & 63, wid = tid >> 6, col = lane & 31, hi = lane >> 5;
    const int hi16 = hi << 4, xr = (col & 7) << 4;
    float dv[2], wv[2];
#pragma unroll
    for (int nf = 0; nf < 2; ++nf) {
        int n = nq * 256 + wid * 64 + nf * 32 + col;
        dv[nf] = dp[b * ATT + n]; wv[nf] = w_e[n];
    }
    const char* bpp = (const char*)BP + (size_t)(nq * 8 + wid * 2) * 1024 + lane * 16;
    f32x16 acc[2][2];
#pragma unroll
    for (int mf = 0; mf < 2; ++mf)
#pragma unroll
        for (int nf = 0; nf < 2; ++nf)
#pragma unroll
            for (int r = 0; r < 16; ++r) acc[mf][nf][r] = 0.0f;
    short8 bb0[2], bb1[2];
    bb0[0] = *(const short8*)(bpp);         bb0[1] = *(const short8*)(bpp + 1024);
    bb1[0] = *(const short8*)(bpp + 32768); bb1[1] = *(const short8*)(bpp + 32768 + 1024);
#pragma unroll
    for (int i = 0; i < 4; ++i) {
        int u = i * 256 + tid, row = u >> 4, fs = u & 15;
        float4 fv = *(const float4*)(enc + ((size_t)(r0 + row) << 10) + (fs << 2));
        s4 v; v[0] = (short)f2bf(fv.x); v[1] = (short)f2bf(fv.y);
              v[2] = (short)f2bf(fv.z); v[3] = (short)f2bf(fv.w);
        *(s4*)((char*)As + row * 128 + ((fs * 8) ^ ((row & 7) << 4))) = v;
    }
    __syncthreads();
#pragma unroll 1
    for (int ph = 0; ph < 16; ++ph) {
        float4 f[4];
        const bool have = (ph < 15);
        if (have) {
#pragma unroll
            for (int i = 0; i < 4; ++i) {
                int u = i * 256 + tid, row = u >> 4, fs = u & 15;
                f[i] = *(const float4*)(enc + ((size_t)(r0 + row) << 10) + ((ph + 1) << 6) + (fs << 2));
            }
        }
        const char* ab    = (const char*)As + ((ph & 1) << 13);
        const char* arow0 = ab + col * 128;
        const char* arow1 = ab + (col + 32) * 128;
        const int kbase = ph << 2;
#pragma unroll
        for (int t = 0; t < 4; t += 2) {
            {
                int off = ((t << 5) + hi16) ^ xr;
                short8 a0 = *(const short8*)(arow0 + off);
                short8 a1 = *(const short8*)(arow1 + off);
                acc[0][0] = __builtin_amdgcn_mfma_f32_32x32x16_bf16(a0, bb0[0], acc[0][0], 0, 0, 0);
                acc[0][1] = __builtin_amdgcn_mfma_f32_32x32x16_bf16(a0, bb0[1], acc[0][1], 0, 0, 0);
                acc[1][0] = __builtin_amdgcn_mfma_f32_32x32x16_bf16(a1, bb0[0], acc[1][0], 0, 0, 0);
                acc[1][1] = __builtin_amdgcn_mfma_f32_32x32x16_bf16(a1, bb0[1], acc[1][1], 0, 0, 0);
                size_t ro = (size_t)((kbase + t + 2) & 63) << 15;
                bb0[0] = *(const short8*)(bpp + ro); bb0[1] = *(const short8*)(bpp + ro + 1024);
            }
            {
                int off = (((t + 1) << 5) + hi16) ^ xr;
                short8 a0 = *(const short8*)(arow0 + off);
                short8 a1 = *(const short8*)(arow1 + off);
                acc[0][0] = __builtin_amdgcn_mfma_f32_32x32x16_bf16(a0, bb1[0], acc[0][0], 0, 0, 0);
                acc[0][1] = __builtin_amdgcn_mfma_f32_32x32x16_bf16(a0, bb1[1], acc[0][1], 0, 0, 0);
                acc[1][0] = __builtin_amdgcn_mfma_f32_32x32x16_bf16(a1, bb1[0], acc[1][0], 0, 0, 0);
                acc[1][1] = __builtin_amdgcn_mfma_f32_32x32x16_bf16(a1, bb1[1], acc[1][1], 0, 0, 0);
                size_t ro = (size_t)((kbase + t + 3) & 63) << 15;
                bb1[0] = *(const short8*)(bpp + ro); bb1[1] = *(const short8*)(bpp + ro + 1024);
            }
        }
        __syncthreads();
        if (have) {
            char* dst = (char*)As + (((ph + 1) & 1) << 13);
#pragma unroll
            for (int i = 0; i < 4; ++i) {
                int u = i * 256 + tid, row = u >> 4, fs = u & 15;
                float4 fv = f[i];
                s4 v; v[0] = (short)f2bf(fv.x); v[1] = (short)f2bf(fv.y);
                      v[2] = (short)f2bf(fv.z); v[3] = (short)f2bf(fv.w);
                *(s4*)(dst + row * 128 + ((fs * 8) ^ ((row & 7) << 4))) = v;
            }
        }
        __syncthreads();
    }
    float ep[32];
#pragma unroll
    for (int mf = 0; mf < 2; ++mf)
#pragma unroll
        for (int reg = 0; reg < 16; ++reg)
            ep[mf * 16 + reg] = fmaf(wv[0], tanh_fast(acc[mf][0][reg] + dv[0]),
                                     wv[1] * tanh_fast(acc[mf][1][reg] + dv[1]));
#pragma unroll
    for (int d = 1; d < 32; d <<= 1)
#pragma unroll
        for (int j = 0; j < 32; ++j)
            ep[j] += __shfl_xor(ep[j], d, 64);
    if (tid < 64) e_lds[tid] = 0.0f;
    __syncthreads();
    if (col == 0) {
#pragma unroll
        for (int j = 0; j < 32; ++j) {
            int reg = j & 15;
            int row = (j >> 4) * 32 + (reg & 3) + 8 * (reg >> 2) + 4 * hi;
            atomicAdd(&e_lds[row], ep[j]);
        }
    }
    __syncthreads();
    if (tid < 64) atomicAdd(&ew[r0 + tid], e_lds[tid]);
}

// ---- softmax: bias + mask + softmax over S, in place; zero context region ----
__global__ void k_softmax(const int* __restrict__ mask, const float* __restrict__ b_e,
                          float* __restrict__ out) {
    int b = blockIdx.x, tid = threadIdx.x;
    float* ew = out + BATCH * ATT + (size_t)b * S_LEN;
    const int* mk = mask + (size_t)b * S_LEN;
    float be = b_e[0];
    float v[8];
#pragma unroll
    for (int i = 0; i < 8; ++i) {
        int s = i * 256 + tid;
        float e = ew[s] + be;
        v[i] = mk[s] ? e : -INFINITY;
    }
    float m = v[0];
#pragma unroll
    for (int i = 1; i < 8; ++i) m = fmaxf(m, v[i]);
#pragma unroll
    for (int d = 1; d < 64; d <<= 1) m = fmaxf(m, __shfl_xor(m, d, 64));
    __shared__ float red[4], red2[4];
    int w = tid >> 6;
    if ((tid & 63) == 0) red[w] = m;
    __syncthreads();
    m = fmaxf(fmaxf(red[0], red[1]), fmaxf(red[2], red[3]));
    float s = 0.0f;
#pragma unroll
    for (int i = 0; i < 8; ++i) { v[i] = __expf(v[i] - m); s += v[i]; }
#pragma unroll
    for (int d = 1; d < 64; d <<= 1) s += __shfl_xor(s, d, 64);
    if ((tid & 63) == 0) red2[w] = s;
    __syncthreads();
    s = red2[0] + red2[1] + red2[2] + red2[3];
    float inv = 1.0f / s;
#pragma unroll
    for (int i = 0; i < 8; ++i) ew[i * 256 + tid] = v[i] * inv;
    float* ctx = out + (size_t)b * ATT;
#pragma unroll
    for (int i = 0; i < 4; ++i) ctx[i * 256 + tid] = 0.0f;
}

// ---- context partials (no atomics): ctxp[b][sx][e] ----
__global__ void k_context_p(const float* __restrict__ enc, const float* __restrict__ wgt,
                            float* __restrict__ ctxp) {
    int sx = blockIdx.x, b = blockIdx.y, tid = threadIdx.x;  // grid (32,32)
    __shared__ float wsh[64];
    if (tid < 64) wsh[tid] = wgt[(size_t)b * S_LEN + sx * 64 + tid];
    __syncthreads();
    const float* ep = enc + ((size_t)b * S_LEN + sx * 64) * ENC2 + tid * 4;
    float ax = 0, ay = 0, az = 0, aw = 0;
    for (int s0 = 0; s0 < 64; s0 += 8) {
        float4 r[8];
#pragma unroll
        for (int j = 0; j < 8; ++j)
            r[j] = *(const float4*)(ep + (size_t)(s0 + j) * ENC2);
#pragma unroll
        for (int j = 0; j < 8; ++j) {
            float w = wsh[s0 + j];
            ax = fmaf(w, r[j].x, ax); ay = fmaf(w, r[j].y, ay);
            az = fmaf(w, r[j].z, az); aw = fmaf(w, r[j].w, aw);
        }
    }
    float4 o; o.x = ax; o.y = ay; o.z = az; o.w = aw;
    *(float4*)(ctxp + ((size_t)b * 32 + sx) * ATT + tid * 4) = o;
}

__global__ void k_ctx_red(const float* __restrict__ ctxp, float* __restrict__ out) {
    int n = blockIdx.x * 256 + threadIdx.x;   // grid (4,32)
    int b = blockIdx.y;
    float s = 0.0f;
#pragma unroll
    for (int sx = 0; sx < 32; ++sx)
        s += ctxp[((size_t)b * 32 + sx) * ATT + n];
    out[(size_t)b * ATT + n] = s;
}

// ---- atomic context fallback ----
__global__ void k_context_a(const float* __restrict__ enc, const float* __restrict__ wgt,
                            float* __restrict__ ctx) {
    int sx = blockIdx.x, b = blockIdx.y, tid = threadIdx.x;
    __shared__ float wsh[64];
    if (tid < 64) wsh[tid] = wgt[(size_t)b * S_LEN + sx * 64 + tid];
    __syncthreads();
    const float* ep = enc + ((size_t)b * S_LEN + sx * 64) * ENC2 + tid * 4;
    float ax = 0, ay = 0, az = 0, aw = 0;
    for (int s0 = 0; s0 < 64; s0 += 8) {
        float4 r[8];
#pragma unroll
        for (int j = 0; j < 8; ++j)
            r[j] = *(const float4*)(ep + (size_t)(s0 + j) * ENC2);
#pragma unroll
        for (int j = 0; j < 8; ++j) {
            float w = wsh[s0 + j];
            ax = fmaf(w, r[j].x, ax); ay = fmaf(w, r[j].y, ay);
            az = fmaf(w, r[j].z, az); aw = fmaf(w, r[j].w, aw);
        }
    }
    float* c = ctx + (size_t)b * ATT + tid * 4;
    atomicAdd(c + 0, ax); atomicAdd(c + 1, ay);
    atomicAdd(c + 2, az); atomicAdd(c + 3, aw);
}

extern "C" void kernel_launch(void* const* d_in, const int* in_sizes, int n_in,
                              void* d_out, int out_size, void* d_ws, size_t ws_size,
                              hipStream_t stream) {
    (void)in_sizes; (void)n_in; (void)out_size;
    const float* dec   = (const float*)d_in[0];
    const float* enc   = (const float*)d_in[1];
    const int*   mask  = (const int*)d_in[2];
    const float* W_enc = (const float*)d_in[3];
    const float* b_enc = (const float*)d_in[4];
    const float* W_dec = (const float*)d_in[5];
    const float* b_dec = (const float*)d_in[6];
    const float* w_e   = (const float*)d_in[7];
    const float* b_e   = (const float*)d_in[8];

    float* out = (float*)d_out;
    unsigned short* BP = (unsigned short*)d_ws;
    float* dp   = (float*)((char*)d_ws + DP_OFF);
    float* ctxp = (float*)((char*)d_ws + CTX_OFF);
    char*  AP   = (char*)d_ws + AP_OFF;
    float* ew   = out + BATCH * ATT;

    const bool fastA = ws_size >= NEED_FULL;
    const bool pctx  = ws_size >= NEED_CTX;

    hipMemsetAsync(ew, 0, (size_t)BATCH * S_LEN * sizeof(float), stream);
    k_pack<<<dim3(64, 8), 256, 0, stream>>>(W_enc, BP);
    k_dproj<<<dim3(4, 32), 256, 0, stream>>>(dec, W_dec, b_dec, b_enc, dp);
    if (fastA) {
        k_cvtA<<<2048, 256, 0, stream>>>(enc, AP);
        k_energy_f<<<4096, 256, 0, stream>>>(AP, (const short*)BP, dp, w_e, ew);
    } else {
        k_energy_v6<<<4096, 256, 0, stream>>>(enc, (const short*)BP, dp, w_e, ew);
    }
    k_softmax<<<32, 256, 0, stream>>>(mask, b_e, out);
    if (pctx) {
        k_context_p<<<dim3(32, 32), 256, 0, stream>>>(enc, ew, ctxp);
        k_ctx_red<<<dim3(4, 32), 256, 0, stream>>>(ctxp, out);
    } else {
        k_context_a<<<dim3(32, 32), 256, 0, stream>>>(enc, ew, out);
    }
}